// Round 9
// baseline (474.516 us; speedup 1.0000x reference)
//
#include <hip/hip_runtime.h>
#include <hip/hip_bf16.h>
#include <stdint.h>

// FusedMoEBlock R8: R7 layouts + pipelined step schedule:
//   per step: pack B(s+1) [loads 1 step old, vmcnt(4) counted] ->
//             issue B(s+2) -> MFMA with A(s) [loaded 2 steps ago] ->
//             issue A(s+2) into freed regs -> raw lgkm barrier.
//   f32->bf16 staging via v_cvt_pk_bf16_f32 (1 inst per pair).
// Layouts: xbK[kblk][t][32], xe[e][kblk][slot][32], act[e][kblk][slot][32],
//          s_act[kblk][t][32]  (kblk = k/32 chunk of 32 bf16 = 64B).
// T=2048,H=2048,E=64,I=512,IS=1024,k<=8.
// d_out = [shared_out (T*H f32) | routed (T*H f32)].

#define H_DIM 2048
#define E_NUM 64
#define I_DIM 512
#define IS_DIM 1024
#define CAPR 288
#define TOPK_MAX 8
#define BK 64
#define LDP 68   // B LDS row stride (u16): 34 dwords == 2 mod 32 -> <=2-way

typedef float f32x4 __attribute__((ext_vector_type(4)));
typedef __bf16 bf16x8 __attribute__((ext_vector_type(8)));

__device__ __forceinline__ uint16_t f2bf(float f) {
  union { float f; uint32_t u; } v;
  v.f = f;
  uint32_t r = (v.u + 0x7FFFu + ((v.u >> 16) & 1u)) >> 16;  // RNE
  return (uint16_t)r;
}
__device__ __forceinline__ uint32_t pack2(float a, float b) {
  return (uint32_t)f2bf(a) | ((uint32_t)f2bf(b) << 16);
}
__device__ __forceinline__ uint32_t cvtpk(float a, float b) {
  uint32_t r;
  asm("v_cvt_pk_bf16_f32 %0, %1, %2" : "=v"(r) : "v"(a), "v"(b));
  return r;  // low16 = bf16(a), high16 = bf16(b)
}
__device__ __forceinline__ float bf2f(uint16_t b) {
  union { uint32_t u; float f; } v;
  v.u = (uint32_t)b << 16;
  return v.f;
}

// barrier WITHOUT vmcnt drain: LDS ops complete, global loads stay in flight
#define BAR()                                              \
  do {                                                     \
    asm volatile("s_waitcnt lgkmcnt(0)" ::: "memory");     \
    __builtin_amdgcn_s_barrier();                          \
    asm volatile("" ::: "memory");                         \
  } while (0)

// ---------------- router: logits/top-k/buckets; writes xbK (k-blocked) -----
__global__ __launch_bounds__(256) void router_kernel(
    const float* __restrict__ x, const float* __restrict__ gw,
    const int* __restrict__ topk_ptr, int* __restrict__ cnt,
    int* __restrict__ bucket, float* __restrict__ bw,
    uint16_t* __restrict__ xbK, const int T) {
  const int t = blockIdx.x;
  const int tid = threadIdx.x;
  __shared__ float xs[H_DIM];
  __shared__ float logits[E_NUM];
#pragma unroll
  for (int i = 0; i < 2; ++i) {
    int idx = tid + i * 256;
    *(float4*)(&xs[idx * 4]) = *(const float4*)(x + (size_t)t * H_DIM + idx * 4);
  }
  __syncthreads();
  {  // f32 -> bf16, k-blocked
    const float* p = &xs[tid * 8];
    uint4 o;
    o.x = pack2(p[0], p[1]);
    o.y = pack2(p[2], p[3]);
    o.z = pack2(p[4], p[5]);
    o.w = pack2(p[6], p[7]);
    *(uint4*)(xbK + (size_t)(tid >> 2) * T * 32 + (size_t)t * 32 +
              (tid & 3) * 8) = o;
  }
  const int lane = tid & 63, wid = tid >> 6;
  float xr[32];
#pragma unroll
  for (int it = 0; it < 32; ++it) xr[it] = xs[lane + 64 * it];
  for (int eo = 0; eo < 16; ++eo) {
    int e = wid + eo * 4;
    const float* g = gw + (size_t)e * H_DIM;
    float acc = 0.f;
#pragma unroll
    for (int it = 0; it < 32; ++it) acc += xr[it] * g[lane + 64 * it];
#pragma unroll
    for (int off = 32; off; off >>= 1) acc += __shfl_xor(acc, off);
    if (lane == 0) logits[e] = acc;
  }
  __syncthreads();
  if (wid == 0) {
    int k = topk_ptr[0];
    if (k > TOPK_MAX) k = TOPK_MAX;
    // sigmoid; pre-topk normalize is scale-invariant -> skipped
    float v = 1.f / (1.f + expf(-logits[lane]));
    float s = 0.f, myw = 0.f;
    int mye = 0;
    for (int j = 0; j < k; ++j) {
      float m = v;
      int mi = lane;
#pragma unroll
      for (int off = 32; off; off >>= 1) {
        float ov = __shfl_xor(m, off);
        int oi = __shfl_xor(mi, off);
        if (ov > m || (ov == m && oi < mi)) { m = ov; mi = oi; }
      }
      if (lane == j) { myw = m; mye = mi; }
      if (lane == mi) v = -1e30f;
      s += m;
    }
    if (lane < k) {
      float w = myw / s;
      int pos = atomicAdd(&cnt[mye], 1);
      if (pos < CAPR) {
        bucket[mye * CAPR + pos] = t * 8 + lane;
        bw[mye * CAPR + pos] = w;
      }
    }
  }
}

// ---------------- gather: xe[e][kblk][slot][32] = xbK[kblk][token][32] -----
__global__ __launch_bounds__(256) void gather_xe(
    const uint16_t* __restrict__ xbK, const int* __restrict__ cnt,
    const int* __restrict__ bucket, uint16_t* __restrict__ xe, const int T) {
  const int e = blockIdx.x;
  const int kgrp = blockIdx.y & 15, sgrp = blockIdx.y >> 4;
  const int tid = threadIdx.x;
  const int slot = sgrp * 64 + (tid & 63);
  const int kblk = kgrp * 4 + (tid >> 6);
  const int n_e = min(cnt[e], CAPR);
  if (slot >= n_e) return;
  const int t = bucket[e * CAPR + slot] >> 3;
  const uint4* src = (const uint4*)(xbK + (size_t)kblk * T * 32 + (size_t)t * 32);
  uint4* dst = (uint4*)(xe + (size_t)e * (64 * CAPR * 32) +
                        (size_t)kblk * (CAPR * 32) + (size_t)slot * 32);
#pragma unroll
  for (int j = 0; j < 4; ++j) dst[j] = src[j];
}

// ---------------- gate+up GEMM + silu*mul -> act (bf16, k-blocked) ---------
template <int BM, bool GATHER>
__global__ __launch_bounds__(256) void ffn_in(
    const uint16_t* __restrict__ A0, const float* __restrict__ Wg,
    const float* __restrict__ Wu, uint16_t* __restrict__ actO,
    const int* __restrict__ cnt, const int K, const int ldb, const int SLOTS) {
  constexpr int BN = 32;
  constexpr int MF = BM / 64;
  constexpr int NF = 2;

  int e = 0, nt, mt0, mtE, n_e;
  const float *Bg, *Bu;
  const uint16_t* AE;
  uint16_t* outE;
  if constexpr (GATHER) {
    e = blockIdx.x;  // gridDim.x=64 -> same-e blocks on XCD e%8
    nt = blockIdx.y;
    n_e = min(cnt[e], CAPR);
    mt0 = 0;
    mtE = (n_e + BM - 1) / BM;
    const size_t wo = (size_t)e * K * ldb;
    Bg = Wg + wo;
    Bu = Wu + wo;
    AE = A0 + (size_t)e * (64 * CAPR * 32);
    outE = actO + (size_t)e * ((I_DIM / 32) * CAPR * 32);
  } else {
    nt = blockIdx.x;
    mt0 = blockIdx.y;
    mtE = mt0 + 1;
    n_e = 1 << 30;
    Bg = Wg;
    Bu = Wu;
    AE = A0;
    outE = actO;
  }
  if (mt0 * BM >= n_e) return;

  __shared__ uint16_t Bgs[2][BN][LDP];
  __shared__ uint16_t Bus[2][BN][LDP];

  const int tid = threadIdx.x;
  const int cg4 = (tid & 7) * 4, kp = tid >> 3;  // 8 col groups x 32 k-pairs
  const float* bgp = Bg + (size_t)(2 * kp) * ldb + nt * BN + cg4;
  const float* bup = Bu + (size_t)(2 * kp) * ldb + nt * BN + cg4;

  const int lane = tid & 63, wid = tid >> 6;
  const int fr = lane & 15, kg = lane >> 4;
  const int wrow = wid * (BM / 4);
  const size_t ldA = (size_t)SLOTS * 32;  // u16 per kblk

  struct BSet { float4 g0, g1, u0, u1; };
  BSet bs0, bs1;
  uint4 aA[MF][2], aB[MF][2];
  const uint16_t* ab[MF];

  auto issueB = [&](BSet& S, int kq) {
    const float* g = bgp + (size_t)kq * ldb;
    S.g0 = *(const float4*)g;
    S.g1 = *(const float4*)(g + ldb);
    const float* u = bup + (size_t)kq * ldb;
    S.u0 = *(const float4*)u;
    S.u1 = *(const float4*)(u + ldb);
  };
  auto packB = [&](int buf, const BSet& S) {
    const int k2 = 2 * kp;
    *(uint32_t*)(&Bgs[buf][cg4 + 0][k2]) = cvtpk(S.g0.x, S.g1.x);
    *(uint32_t*)(&Bgs[buf][cg4 + 1][k2]) = cvtpk(S.g0.y, S.g1.y);
    *(uint32_t*)(&Bgs[buf][cg4 + 2][k2]) = cvtpk(S.g0.z, S.g1.z);
    *(uint32_t*)(&Bgs[buf][cg4 + 3][k2]) = cvtpk(S.g0.w, S.g1.w);
    *(uint32_t*)(&Bus[buf][cg4 + 0][k2]) = cvtpk(S.u0.x, S.u1.x);
    *(uint32_t*)(&Bus[buf][cg4 + 1][k2]) = cvtpk(S.u0.y, S.u1.y);
    *(uint32_t*)(&Bus[buf][cg4 + 2][k2]) = cvtpk(S.u0.z, S.u1.z);
    *(uint32_t*)(&Bus[buf][cg4 + 3][k2]) = cvtpk(S.u0.w, S.u1.w);
  };
  auto issueA = [&](uint4 (&A)[MF][2], int s) {
#pragma unroll
    for (int mf = 0; mf < MF; ++mf)
#pragma unroll
      for (int sl = 0; sl < 2; ++sl)
        A[mf][sl] = *(const uint4*)(ab[mf] + (size_t)(2 * s + sl) * ldA);
  };

  f32x4 accg[MF][NF];
  f32x4 accu[MF][NF];

  auto mfmaStep = [&](int buf, uint4 (&A)[MF][2]) {
#pragma unroll
    for (int sl = 0; sl < 2; ++sl)
#pragma unroll
      for (int nf = 0; nf < NF; ++nf) {
        const bf16x8 bg = __builtin_bit_cast(
            bf16x8, *(const uint4*)(&Bgs[buf][nf * 16 + fr][kg * 8 + sl * 32]));
        const bf16x8 bu = __builtin_bit_cast(
            bf16x8, *(const uint4*)(&Bus[buf][nf * 16 + fr][kg * 8 + sl * 32]));
#pragma unroll
        for (int mf = 0; mf < MF; ++mf) {
          const bf16x8 af = __builtin_bit_cast(bf16x8, A[mf][sl]);
          accg[mf][nf] = __builtin_amdgcn_mfma_f32_16x16x32_bf16(
              af, bg, accg[mf][nf], 0, 0, 0);
          accu[mf][nf] = __builtin_amdgcn_mfma_f32_16x16x32_bf16(
              af, bu, accu[mf][nf], 0, 0, 0);
        }
      }
  };

  const int NS = K / BK;  // even
  for (int mt = mt0; mt < mtE; ++mt) {
#pragma unroll
    for (int mf = 0; mf < MF; ++mf)
      ab[mf] = AE + (size_t)(mt * BM + wrow + mf * 16 + fr) * 32 + kg * 8;
#pragma unroll
    for (int mf = 0; mf < MF; ++mf)
#pragma unroll
      for (int nf = 0; nf < NF; ++nf) {
        accg[mf][nf] = (f32x4){0.f, 0.f, 0.f, 0.f};
        accu[mf][nf] = (f32x4){0.f, 0.f, 0.f, 0.f};
      }

    // prologue: B(0)->lds0, A(0); issue B(1), A(1)
    issueB(bs0, 0);
    issueA(aA, 0);
    packB(0, bs0);          // vmcnt counted (A(0) stays outstanding)
    issueB(bs1, BK);
    issueA(aB, 1);
    BAR();

    for (int s = 0; s < NS; s += 2) {
      // even step s: lds0 current, pack lds1 from bs1
      if (s + 1 < NS) packB(1, bs1);
      if (s + 2 < NS) issueB(bs0, (s + 2) * BK);
      mfmaStep(0, aA);
      if (s + 2 < NS) issueA(aA, s + 2);
      BAR();
      // odd step s+1: lds1 current, pack lds0 from bs0
      if (s + 2 < NS) packB(0, bs0);
      if (s + 3 < NS) issueB(bs1, (s + 3) * BK);
      mfmaStep(1, aB);
      if (s + 3 < NS) issueA(aB, s + 3);
      BAR();
    }

    // epilogue: k-blocked act write
#pragma unroll
    for (int mf = 0; mf < MF; ++mf)
#pragma unroll
      for (int rr = 0; rr < 4; ++rr) {
        const int slot = mt * BM + wrow + mf * 16 + kg * 4 + rr;
        if (slot < n_e) {
          uint16_t* op = outE + (size_t)nt * ldA + (size_t)slot * 32 + fr;
#pragma unroll
          for (int nf = 0; nf < NF; ++nf) {
            const float g = accg[mf][nf][rr], u = accu[mf][nf][rr];
            op[nf * 16] = f2bf(g / (1.f + expf(-g)) * u);
          }
        }
      }
  }
}

// ---------------- down GEMM; GATHER -> weighted bf16 rows into ybuf --------
template <int BM, bool GATHER>
__global__ __launch_bounds__(256) void ffn_down(
    const uint16_t* __restrict__ A0, const float* __restrict__ Wd,
    void* __restrict__ outp, const int* __restrict__ cnt,
    const int* __restrict__ bucket, const float* __restrict__ bw,
    const int K, const int SLOTS) {
  constexpr int BN = 64;
  constexpr int MF = BM / 64;
  constexpr int NF = 4;

  int e = 0, nt, mt0, mtE, n_e;
  const float* Bd;
  const uint16_t* AE;
  if constexpr (GATHER) {
    e = blockIdx.x;
    nt = blockIdx.y;
    n_e = min(cnt[e], CAPR);
    mt0 = 0;
    mtE = (n_e + BM - 1) / BM;
    AE = A0 + (size_t)e * ((I_DIM / 32) * CAPR * 32);
    Bd = Wd + (size_t)e * K * H_DIM;
  } else {
    nt = blockIdx.x;
    mt0 = blockIdx.y;
    mtE = mt0 + 1;
    n_e = 1 << 30;
    AE = A0;
    Bd = Wd;
  }
  if (mt0 * BM >= n_e) return;

  __shared__ uint16_t Bs[2][BN][LDP];

  const int tid = threadIdx.x;
  const int cg4 = (tid & 15) * 4, kp = tid >> 4;  // 16 col groups x 16 kpairs
  const float* bdp = Bd + (size_t)(2 * kp) * H_DIM + nt * BN + cg4;

  const int lane = tid & 63, wid = tid >> 6;
  const int fr = lane & 15, kg = lane >> 4;
  const int wrow = wid * (BM / 4);
  const size_t ldA = (size_t)SLOTS * 32;

  struct DSet { float4 d0[2], d1[2]; };
  DSet bs0, bs1;
  uint4 aA[MF][2], aB[MF][2];
  const uint16_t* ab[MF];

  auto issueB = [&](DSet& S, int kq) {
#pragma unroll
    for (int pp = 0; pp < 2; ++pp) {
      const float* d = bdp + (size_t)(kq + 2 * pp * 16) * H_DIM;
      S.d0[pp] = *(const float4*)d;
      S.d1[pp] = *(const float4*)(d + H_DIM);
    }
  };
  auto packB = [&](int buf, const DSet& S) {
#pragma unroll
    for (int pp = 0; pp < 2; ++pp) {
      const int k2 = 2 * (kp + pp * 16);
      *(uint32_t*)(&Bs[buf][cg4 + 0][k2]) = cvtpk(S.d0[pp].x, S.d1[pp].x);
      *(uint32_t*)(&Bs[buf][cg4 + 1][k2]) = cvtpk(S.d0[pp].y, S.d1[pp].y);
      *(uint32_t*)(&Bs[buf][cg4 + 2][k2]) = cvtpk(S.d0[pp].z, S.d1[pp].z);
      *(uint32_t*)(&Bs[buf][cg4 + 3][k2]) = cvtpk(S.d0[pp].w, S.d1[pp].w);
    }
  };
  auto issueA = [&](uint4 (&A)[MF][2], int s) {
#pragma unroll
    for (int mf = 0; mf < MF; ++mf)
#pragma unroll
      for (int sl = 0; sl < 2; ++sl)
        A[mf][sl] = *(const uint4*)(ab[mf] + (size_t)(2 * s + sl) * ldA);
  };

  f32x4 acc[MF][NF];

  auto mfmaStep = [&](int buf, uint4 (&A)[MF][2]) {
#pragma unroll
    for (int sl = 0; sl < 2; ++sl)
#pragma unroll
      for (int nf = 0; nf < NF; ++nf) {
        const bf16x8 bf_ = __builtin_bit_cast(
            bf16x8, *(const uint4*)(&Bs[buf][nf * 16 + fr][kg * 8 + sl * 32]));
#pragma unroll
        for (int mf = 0; mf < MF; ++mf) {
          const bf16x8 af = __builtin_bit_cast(bf16x8, A[mf][sl]);
          acc[mf][nf] = __builtin_amdgcn_mfma_f32_16x16x32_bf16(
              af, bf_, acc[mf][nf], 0, 0, 0);
        }
      }
  };

  const int NS = K / BK;  // even
  for (int mt = mt0; mt < mtE; ++mt) {
#pragma unroll
    for (int mf = 0; mf < MF; ++mf)
      ab[mf] = AE + (size_t)(mt * BM + wrow + mf * 16 + fr) * 32 + kg * 8;
#pragma unroll
    for (int mf = 0; mf < MF; ++mf)
#pragma unroll
      for (int nf = 0; nf < NF; ++nf) acc[mf][nf] = (f32x4){0.f, 0.f, 0.f, 0.f};

    issueB(bs0, 0);
    issueA(aA, 0);
    packB(0, bs0);
    issueB(bs1, BK);
    issueA(aB, 1);
    BAR();

    for (int s = 0; s < NS; s += 2) {
      if (s + 1 < NS) packB(1, bs1);
      if (s + 2 < NS) issueB(bs0, (s + 2) * BK);
      mfmaStep(0, aA);
      if (s + 2 < NS) issueA(aA, s + 2);
      BAR();
      if (s + 2 < NS) packB(0, bs0);
      if (s + 3 < NS) issueB(bs1, (s + 3) * BK);
      mfmaStep(1, aB);
      if (s + 3 < NS) issueA(aB, s + 3);
      BAR();
    }

    const int col0 = nt * BN + fr;
#pragma unroll
    for (int mf = 0; mf < MF; ++mf)
#pragma unroll
      for (int rr = 0; rr < 4; ++rr) {
        const int slot = mt * BM + wrow + mf * 16 + kg * 4 + rr;
        if constexpr (GATHER) {
          if (slot < n_e) {
            const int bv = bucket[e * CAPR + slot];
            const float w = bw[e * CAPR + slot];
            uint16_t* yb = (uint16_t*)outp + (size_t)bv * H_DIM + col0;
#pragma unroll
            for (int nf = 0; nf < NF; ++nf)
              yb[nf * 16] = f2bf(w * acc[mf][nf][rr]);
          }
        } else {
          float* op = (float*)outp + (size_t)slot * H_DIM + col0;
#pragma unroll
          for (int nf = 0; nf < NF; ++nf) op[nf * 16] = acc[mf][nf][rr];
        }
      }
  }
}

// ---------------- combine: routed[t] = sum_{j<k} ybuf[t*8+j] ----------------
__global__ __launch_bounds__(256) void combine_kernel(
    const uint16_t* __restrict__ ybuf, const int* __restrict__ topk_ptr,
    float* __restrict__ routed) {
  const int t = blockIdx.x;
  const int tid = threadIdx.x;
  int k = topk_ptr[0];
  if (k > TOPK_MAX) k = TOPK_MAX;
  float acc[8] = {};
  const uint16_t* base = ybuf + (size_t)t * 8 * H_DIM + tid * 8;
  for (int j = 0; j < k; ++j) {
    uint4 v = *(const uint4*)(base + (size_t)j * H_DIM);
    const uint16_t* h = (const uint16_t*)&v;
#pragma unroll
    for (int i = 0; i < 8; ++i) acc[i] += bf2f(h[i]);
  }
  float* op = routed + (size_t)t * H_DIM + tid * 8;
  *(float4*)op = make_float4(acc[0], acc[1], acc[2], acc[3]);
  *(float4*)(op + 4) = make_float4(acc[4], acc[5], acc[6], acc[7]);
}

extern "C" void kernel_launch(void* const* d_in, const int* in_sizes, int n_in,
                              void* d_out, int out_size, void* d_ws, size_t ws_size,
                              hipStream_t stream) {
  const float* x = (const float*)d_in[0];
  const float* gw = (const float*)d_in[1];
  const float* w_gate = (const float*)d_in[2];
  const float* w_up = (const float*)d_in[3];
  const float* w_down = (const float*)d_in[4];
  const float* sw_gate = (const float*)d_in[5];
  const float* sw_up = (const float*)d_in[6];
  const float* sw_down = (const float*)d_in[7];
  const int* topk = (const int*)d_in[8];
  const int T = in_sizes[0] / H_DIM;  // 2048

  float* shared_out = (float*)d_out;
  float* routed = shared_out + (size_t)T * H_DIM;

  char* ws = (char*)d_ws;
  size_t off = 0;
  auto take = [&](size_t b) {
    char* p = ws + off;
    off += (b + 255) & ~(size_t)255;
    return p;
  };
  uint16_t* xbK = (uint16_t*)take((size_t)T * H_DIM * 2);                // 8.4 MB
  int* cnt = (int*)take(E_NUM * 4);
  int* bucket = (int*)take((size_t)E_NUM * CAPR * 4);
  float* bw = (float*)take((size_t)E_NUM * CAPR * 4);
  uint16_t* xe = (uint16_t*)take((size_t)E_NUM * 64 * CAPR * 32 * 2 + 65536);   // 75.5 MB
  uint16_t* act = (uint16_t*)take((size_t)E_NUM * 16 * CAPR * 32 * 2 + 65536);  // 18.9 MB
  uint16_t* s_act = (uint16_t*)take((size_t)(IS_DIM / 32) * T * 32 * 2);        // 4.2 MB
  uint16_t* ybuf = (uint16_t*)take((size_t)T * 8 * H_DIM * 2);                  // 67 MB

  hipMemsetAsync(cnt, 0, E_NUM * 4, stream);

  router_kernel<<<T, 256, 0, stream>>>(x, gw, topk, cnt, bucket, bw, xbK, T);
  gather_xe<<<dim3(E_NUM, 16 * ((CAPR + 63) / 64)), 256, 0, stream>>>(
      xbK, cnt, bucket, xe, T);

  // grouped gate+up: BM=256 (weights streamed once), grid (e, nt)
  ffn_in<256, true><<<dim3(E_NUM, I_DIM / 32), 256, 0, stream>>>(
      xe, w_gate, w_up, act, cnt, H_DIM, I_DIM, CAPR);
  // grouped down: BM=256 BN=64 -> weighted bf16 rows in ybuf
  ffn_down<256, true><<<dim3(E_NUM, H_DIM / 64), 256, 0, stream>>>(
      act, w_down, (void*)ybuf, cnt, bucket, bw, I_DIM, CAPR);
  // combine routed
  combine_kernel<<<T, 256, 0, stream>>>(ybuf, topk, routed);
  // shared gate+up: BM=128, grid (nt, mt)
  ffn_in<128, false><<<dim3(IS_DIM / 32, T / 128), 256, 0, stream>>>(
      xbK, sw_gate, sw_up, s_act, nullptr, H_DIM, IS_DIM, T);
  // shared down: BM=128 -> shared_out (f32)
  ffn_down<128, false><<<dim3(H_DIM / 64, T / 128), 256, 0, stream>>>(
      s_act, sw_down, (void*)shared_out, nullptr, nullptr, nullptr, IS_DIM, T);
}